// Round 9
// baseline (158.406 us; speedup 1.0000x reference)
//
#include <hip/hip_runtime.h>

// Problem constants (from reference): B,R,C,H,W = 4,2,19,256,512
constexpr int B = 4, R = 2, C = 19, H = 256, W = 512;
constexpr int HW = H * W;

// R9: TWO CHANNELS PER PHASE (same tap state), 64x16/256thr base from R7.
// Falsified so far (dispatch us): staging-path (R1 51.4), bank mapping
// (R2/R5, conflicts invariant 5.4M), drain hiding/dbuf (R4 52.5), no-LDS
// (R6 101.6), LDS-capacity occupancy (R7 49.0), waves/WG + phase count +
// staged-byte volume (R8 50.3: -28% bytes, -50% phases -> +0). No pipe
// saturated (VALU ~21%, HBM ~24%, LDS ~35-40%) -> remaining hypothesis:
// per-wave latency chains (gathers not deep enough to cover ds latency at
// ~2.5 issuing waves/SIMD). This round doubles independent LDS loads per
// wave-phase (2 channels x 16 taps before any dependent FMA) at identical
// total work. Null => structure converged; wall unattributable further.
//
// PIXEL->THREAD MAP (R5, proven): wave w (= t>>6) owns rows y0+4w+p
// (p=0..3); lane (= t&63) is the x offset. mv/wgt loads and out stores are
// 256B wave ops.
constexpr int BX = 64, BY = 16;
constexpr int NBX = W / BX;              // 8
constexpr int NBY = H / BY;              // 16
constexpr int NSPAT = B * NBX * NBY;     // 512 spatial tiles
constexpr int NCHUNK = 4;                // 2048 blocks = 8/CU queued

// Pred tiles in LDS: [channel-slot 0/1][ref 0/1], single-buffered per pair.
// Halo: x in [-12,+11] (colbase = x0-12, float4-aligned), y in [-10,+10].
// 4 tiles x 13.02 KB = 52.1 KB/block -> 3 blocks/CU.
constexpr int TW = 88;                   // 22 float4s per row
constexpr int TH = 37;                   // 16 + 10 up + 11 down
constexpr int TILE_N = TW * TH;          // 3256 floats = 13.02 KB
constexpr int TILE_V4 = TILE_N / 4;      // 814 float4s
// TW = 22*4 exactly -> tile rows pack contiguously: phys float index of the
// idx-th float4 is idx*4, i.e. exactly the wave-linear layout global_load_lds
// needs (uniform LDS base + lane*16B, per-lane GLOBAL source address).

// Direct global->LDS DMA, 16B per lane. No VGPR round-trip (register staging
// buffers spill to scratch: proven 2.4-3x slower, twice).
#define GLD_LDS16(gsrc, ldst)                                                  \
    __builtin_amdgcn_global_load_lds(                                          \
        (const __attribute__((address_space(1))) void*)(gsrc),                 \
        (__attribute__((address_space(3))) void*)(ldst), 16, 0, 0)

// Register regime: launch_bounds(256,4) = VGPR cap 128 (proven zero-spill
// regime; this round's 2-channel inner loop pushes live state to ~90-110 --
// still under cap). DO NOT tighten the bound (R2: cap -> VGPR 40 ->
// tap-state spill -> 3x slower). Spill tripwire: WRITE_SIZE >> 39 MB.
//
// SYNC RULE (R3 failure, absmax 6.06): __syncthreads_or does NOT carry the
// vmcnt(0) drain that __syncthreads does. Every global_load_lds -> ds_read
// handoff MUST cross a plain __syncthreads().
__global__ __launch_bounds__(256, 4) void mc_warp_kernel(
    const float* __restrict__ pred,   // [B,R,C,H,W]
    const float* __restrict__ mv,     // [B,R,2,H,W] quarter-pel
    const float* __restrict__ wgt,    // [B,R,1,H,W]
    float* __restrict__ out)          // [B,C,H,W]
{
    __shared__ float tiles[2][2][TILE_N];   // [ch-slot][ref][tile]

    int t = threadIdx.x;
    // XCD band swizzle on the spatial index: each XCD owns a contiguous
    // (b, y-band); all channel-chunks of a tile land on the same XCD
    // (gridDim.x = 512 is a multiple of 8) -> pred/mv/wgt L2 locality.
    int xcd  = blockIdx.x & 7;
    int slot = blockIdx.x >> 3;
    int vblk = xcd * (NSPAT / 8) + slot;
    int bx   = vblk & (NBX - 1);
    int by   = (vblk >> 3) & (NBY - 1);
    int b    = vblk >> 7;
    int x0 = bx * BX, y0 = by * BY;
    int lane = t & 63, wv = t >> 6;
    int x  = x0 + lane;                  // this thread's x (all 4 px share it)
    int yb = y0 + wv * 4;                // px p of this thread = row yb + p

    // Tile origin, clamped fully inside the image (staging needs no clamps).
    // colbase stays float4-aligned (x0 mult of 64, W-TW = 424 mult of 4).
    int rowbase = min(max(y0 - 10, 0), H - TH);
    int colbase = min(max(x0 - 12, 0), W - TW);

    const float* pl0 = pred + (size_t)(b * R + 0) * C * HW;
    const float* pl1 = pred + (size_t)(b * R + 1) * C * HW;
    const float* st0 = pl0 + (size_t)rowbase * W + colbase;
    const float* st1 = pl1 + (size_t)rowbase * W + colbase;

    int cbeg = (C * blockIdx.y) / NCHUNK;        // {0,4,9,14}
    int cend = (C * (blockIdx.y + 1)) / NCHUNK;  // {4,9,14,19} (sizes 4,5,5,5)

    // Stage one channel into ch-slot cs (both refs). Wave-linear DMA.
    auto STAGE = [&](int c, int cs) {
        const float* s0 = st0 + (size_t)c * HW;
        const float* s1 = st1 + (size_t)c * HW;
        #pragma unroll
        for (int i = 0; i < 4; ++i) {
            int idx = t + i * 256;
            if (idx < TILE_V4) {
                int row = idx / 22;               // 22 float4s per tile row
                int off = idx * 4 + row * (W - TW);   // == row*W + c4
                GLD_LDS16(s0 + off, &tiles[cs][0][idx * 4]);
                GLD_LDS16(s1 + off, &tiles[cs][1][idx * 4]);
            }
        }
    };

    // Prologue: stage the first channel PAIR now; overlaps the ~300-op tap
    // setup below; drained by the first loop-body __syncthreads().
    // (cbeg+1 < cend always: min chunk size is 4.)
    STAGE(cbeg, 0);
    STAGE(cbeg + 1, 1);

    // Per-(ref, px) tap state: two row-pair offsets + 4 pair weights.
    // Channel-invariant: computed once, reused for all channels.
    int   off0[R][4], off1[R][4];
    int   offL0[R][4], offL1[R][4], offG0[R][4], offG1[R][4];
    float wq[R][4][4];
    int flag = 0;

    #pragma unroll
    for (int r = 0; r < R; ++r) {
        const float* mvx = mv + (size_t)((b * R + r) * 2) * HW;
        const float* mvy = mvx + HW;
        const float* wp  = wgt + (size_t)(b * R + r) * HW;
        #pragma unroll
        for (int p = 0; p < 4; ++p) {
            int yy = yb + p;
            size_t ro = (size_t)yy * W + x;       // 256B-coalesced per wave
            float mx = mvx[ro], my = mvy[ro], wr = wp[ro];

            float gx = (float)x  + mx * 0.25f;    // quarter-pel -> pixel
            float gy = (float)yy + my * 0.25f;
            float fx0 = floorf(gx), fy0 = floorf(gy);
            float wx1 = gx - fx0, wx0 = 1.0f - wx1;
            float wy1 = gy - fy0, wy0 = 1.0f - wy1;
            int ix0 = (int)fx0, iy0 = (int)fy0;
            int ix1 = ix0 + 1,  iy1 = iy0 + 1;

            // x pair: shift base into [0, W-2], route wx0/wx1 per element.
            int base = min(max(ix0, 0), W - 2);
            float wA = (ix0 == base)     ? wx0 : ((ix1 == base)     ? wx1 : 0.0f);
            float wB = (ix1 == base + 1) ? wx1 : ((ix0 == base + 1) ? wx0 : 0.0f);
            float wy0v = ((iy0 >= 0) && (iy0 < H)) ? wy0 * wr : 0.0f;
            float wy1v = ((iy1 >= 0) && (iy1 < H)) ? wy1 * wr : 0.0f;
            int cy0 = min(max(iy0, 0), H - 1);
            int cy1 = min(max(iy1, 0), H - 1);

            int l0 = base - colbase;
            int r0 = cy0 - rowbase, r1 = cy1 - rowbase;
            bool anyx = (wA != 0.0f) || (wB != 0.0f);
            bool anyy = (wy0v != 0.0f) || (wy1v != 0.0f);
            bool cb  = (l0 < 0 || l0 > TW - 2) && anyx && anyy;
            bool rb0 = (r0 < 0 || r0 > TH - 1) && (wy0v != 0.0f) && anyx;
            bool rb1 = (r1 < 0 || r1 > TH - 1) && (wy1v != 0.0f) && anyx;
            flag |= (int)(cb || rb0 || rb1);
            l0 = min(max(l0, 0), TW - 2);
            r0 = min(max(r0, 0), TH - 1);
            r1 = min(max(r1, 0), TH - 1);

            offL0[r][p] = r0 * TW + l0;
            offL1[r][p] = r1 * TW + l0;
            offG0[r][p] = cy0 * W + base;
            offG1[r][p] = cy1 * W + base;
            wq[r][p][0] = wy0v * wA;
            wq[r][p][1] = wy0v * wB;
            wq[r][p][2] = wy1v * wA;
            wq[r][p][3] = wy1v * wB;
        }
    }

    // Block-uniform fallback: if ANY tap escaped the halo, the whole block
    // uses global gathers instead of LDS. Flag reduction ONLY — memory
    // ordering comes from the plain __syncthreads() in the loop.
    int fbB = __syncthreads_or(flag);
    #pragma unroll
    for (int r = 0; r < R; ++r)
        #pragma unroll
        for (int p = 0; p < 4; ++p) {
            off0[r][p] = fbB ? offG0[r][p] : offL0[r][p];
            off1[r][p] = fbB ? offG1[r][p] : offL1[r][p];
        }

    float* ob = out + (size_t)b * C * HW + (size_t)yb * W + x;

    for (int c = cbeg; c < cend; c += 2) {
        bool has2 = (c + 1 < cend);      // block-uniform
        if (c > cbeg) {
            __syncthreads();             // previous pair's LDS readers done
            if (!fbB) {
                STAGE(c, 0);
                if (has2) STAGE(c + 1, 1);
            }
        }
        __syncthreads();                 // drains stage (vmcnt0 + barrier)

        if (!fbB) {
            const float* a0 = &tiles[0][0][0];   // ch c,   ref 0
            const float* a1 = &tiles[0][1][0];   // ch c,   ref 1
            const float* c0 = &tiles[1][0][0];   // ch c+1, ref 0
            const float* c1 = &tiles[1][1][0];   // ch c+1, ref 1
            if (has2) {
                // Full pair: one straight-line block -> 32 independent LDS
                // loads in flight before the FMA trees (the MLP probe).
                float res0[4], res1[4];
                #pragma unroll
                for (int p = 0; p < 4; ++p) {
                    int o00 = off0[0][p], o01 = off1[0][p];
                    int o10 = off0[1][p], o11 = off1[1][p];
                    float x00 = a0[o00], x01 = a0[o00 + 1];
                    float x10 = a0[o01], x11 = a0[o01 + 1];
                    float y00 = a1[o10], y01 = a1[o10 + 1];
                    float y10 = a1[o11], y11 = a1[o11 + 1];
                    float u00 = c0[o00], u01 = c0[o00 + 1];
                    float u10 = c0[o01], u11 = c0[o01 + 1];
                    float v00 = c1[o10], v01 = c1[o10 + 1];
                    float v10 = c1[o11], v11 = c1[o11 + 1];
                    res0[p] = wq[0][p][0] * x00 + wq[0][p][1] * x01
                            + wq[0][p][2] * x10 + wq[0][p][3] * x11
                            + wq[1][p][0] * y00 + wq[1][p][1] * y01
                            + wq[1][p][2] * y10 + wq[1][p][3] * y11;
                    res1[p] = wq[0][p][0] * u00 + wq[0][p][1] * u01
                            + wq[0][p][2] * u10 + wq[0][p][3] * u11
                            + wq[1][p][0] * v00 + wq[1][p][1] * v01
                            + wq[1][p][2] * v10 + wq[1][p][3] * v11;
                }
                float* oc0 = ob + (size_t)c * HW;
                float* oc1 = ob + (size_t)(c + 1) * HW;
                #pragma unroll
                for (int p = 0; p < 4; ++p) {
                    oc0[(size_t)p * W] = res0[p];
                    oc1[(size_t)p * W] = res1[p];
                }
            } else {
                // Tail single channel.
                float res0[4];
                #pragma unroll
                for (int p = 0; p < 4; ++p) {
                    int o00 = off0[0][p], o01 = off1[0][p];
                    int o10 = off0[1][p], o11 = off1[1][p];
                    float x00 = a0[o00], x01 = a0[o00 + 1];
                    float x10 = a0[o01], x11 = a0[o01 + 1];
                    float y00 = a1[o10], y01 = a1[o10 + 1];
                    float y10 = a1[o11], y11 = a1[o11 + 1];
                    res0[p] = wq[0][p][0] * x00 + wq[0][p][1] * x01
                            + wq[0][p][2] * x10 + wq[0][p][3] * x11
                            + wq[1][p][0] * y00 + wq[1][p][1] * y01
                            + wq[1][p][2] * y10 + wq[1][p][3] * y11;
                }
                float* oc0 = ob + (size_t)c * HW;
                #pragma unroll
                for (int p = 0; p < 4; ++p)
                    oc0[(size_t)p * W] = res0[p];
            }
        } else {
            // Fallback: global gathers, one channel at a time (rare).
            for (int cc = c; cc < min(c + 2, cend); ++cc) {
                const float* pc0 = pl0 + (size_t)cc * HW;
                const float* pc1 = pl1 + (size_t)cc * HW;
                float res[4];
                #pragma unroll
                for (int p = 0; p < 4; ++p) {
                    float a00 = pc0[off0[0][p]], a01 = pc0[off0[0][p] + 1];
                    float a10 = pc0[off1[0][p]], a11 = pc0[off1[0][p] + 1];
                    float b00 = pc1[off0[1][p]], b01 = pc1[off0[1][p] + 1];
                    float b10 = pc1[off1[1][p]], b11 = pc1[off1[1][p] + 1];
                    res[p] = wq[0][p][0] * a00 + wq[0][p][1] * a01
                           + wq[0][p][2] * a10 + wq[0][p][3] * a11
                           + wq[1][p][0] * b00 + wq[1][p][1] * b01
                           + wq[1][p][2] * b10 + wq[1][p][3] * b11;
                }
                float* oc = ob + (size_t)cc * HW;
                #pragma unroll
                for (int p = 0; p < 4; ++p)
                    oc[(size_t)p * W] = res[p];
            }
        }
    }
}

extern "C" void kernel_launch(void* const* d_in, const int* in_sizes, int n_in,
                              void* d_out, int out_size, void* d_ws, size_t ws_size,
                              hipStream_t stream) {
    const float* pred = (const float*)d_in[0];   // [B,R,C,H,W] fp32
    const float* mv   = (const float*)d_in[1];   // [B,R,2,H,W] fp32
    const float* wgt  = (const float*)d_in[2];   // [B,R,1,H,W] fp32
    float* out = (float*)d_out;                  // [B,C,H,W] fp32

    dim3 grid(NSPAT, NCHUNK);            // 512 spatial tiles x 4 channel chunks
    mc_warp_kernel<<<grid, dim3(256), 0, stream>>>(pred, mv, wgt, out);
}

// Round 10
// 157.183 us; speedup vs baseline: 1.0078x; 1.0078x over previous
//
#include <hip/hip_runtime.h>

// Problem constants (from reference): B,R,C,H,W = 4,2,19,256,512
constexpr int B = 4, R = 2, C = 19, H = 256, W = 512;
constexpr int HW = H * W;

// R10 = R7 (session best, 49.0 us) + two riders:
//  (1) DEFERRED STORES: every loop-top __syncthreads() compiles to
//      s_waitcnt vmcnt(0)+barrier, and vmcnt counts the previous phase's 4
//      global stores -> each of ~38 phases/CU serially paid a store-ack
//      round trip. Results now accumulate in registers (res[5][4], 20 VGPR,
//      STATIC indexing via guarded unroll -- runtime-indexed arrays go to
//      scratch) and are stored in a barrier-free epilogue.
//  (2) s_setprio(1) around gather+FMA: blocks here are independent (attn-like
//      regime, measured +4-7%), not barrier-lockstepped (GEMM null regime).
//
// LEDGER (dispatch us): R1 51.4 single-buf | R2 147 REGRESSION (reg-cap spill)
// | R4 52.5 dbuf | R5 53 remap (conflicts invariant -> staging-DMA-inherent)
// | R6 101.6 no-LDS (2x WORSE) | R7 49.0 lean single-buf | R8 50.3 8-wave
// (waves/WG, phase count, staged bytes all null) | R9 59.1 2-ch ILP
// (VGPR 128 -> occupancy halved; register cost fatal).
//
// PIXEL->THREAD MAP (R5, proven): wave w (= t>>6) owns rows y0+4w+p
// (p=0..3); lane (= t&63) is the x offset. mv/wgt loads and out stores are
// 256B wave ops.
constexpr int BX = 64, BY = 16;
constexpr int NBX = W / BX;              // 8
constexpr int NBY = H / BY;              // 16
constexpr int NSPAT = B * NBX * NBY;     // 512 spatial tiles
constexpr int NCHUNK = 4;                // 2048 blocks = 8/CU queued
constexpr int MAXCH = 5;                 // max channels per chunk

// Pred tile staged in LDS per (channel, ref), SINGLE-buffered.
// Halo: x in [-12,+11] (colbase = x0-12, float4-aligned), y in [-10,+10].
// Escape prob ~1e-6/px-ref -> ~0.25% of blocks take the (correct) global
// fallback. 2 tiles x 13.02 KB = 26.05 KB/block.
constexpr int TW = 88;                   // 22 float4s per row
constexpr int TH = 37;                   // 16 + 10 up + 11 down
constexpr int TILE_N = TW * TH;          // 3256 floats = 13.02 KB
constexpr int TILE_V4 = TILE_N / 4;      // 814 float4s
// TW = 22*4 exactly -> tile rows pack contiguously: phys float index of the
// idx-th float4 is idx*4, i.e. exactly the wave-linear layout global_load_lds
// needs (uniform LDS base + lane*16B, per-lane GLOBAL source address).

// Direct global->LDS DMA, 16B per lane. No VGPR round-trip (register staging
// buffers spill to scratch: proven 2.4-3x slower, twice).
#define GLD_LDS16(gsrc, ldst)                                                  \
    __builtin_amdgcn_global_load_lds(                                          \
        (const __attribute__((address_space(1))) void*)(gsrc),                 \
        (__attribute__((address_space(3))) void*)(ldst), 16, 0, 0)

// Register regime: launch_bounds(256,4) = VGPR cap 128. R7 compiled to 64;
// +20 res registers -> ~84-96 expected, still under cap with zero spill.
// DO NOT tighten the bound (R2: VGPR 40 + tap-state spill, 3x slower).
// Spill tripwire: WRITE_SIZE >> 39 MB.
//
// SYNC RULE (R3 failure, absmax 6.06): __syncthreads_or does NOT carry the
// vmcnt(0) drain that __syncthreads does. Every global_load_lds -> ds_read
// handoff MUST cross a plain __syncthreads().
__global__ __launch_bounds__(256, 4) void mc_warp_kernel(
    const float* __restrict__ pred,   // [B,R,C,H,W]
    const float* __restrict__ mv,     // [B,R,2,H,W] quarter-pel
    const float* __restrict__ wgt,    // [B,R,1,H,W]
    float* __restrict__ out)          // [B,C,H,W]
{
    __shared__ float tiles[2][TILE_N];   // [ref][tile], single-buffered

    int t = threadIdx.x;
    // XCD band swizzle on the spatial index: each XCD owns a contiguous
    // (b, y-band); all channel-chunks of a tile land on the same XCD
    // (gridDim.x = 512 is a multiple of 8) -> pred/mv/wgt L2 locality.
    int xcd  = blockIdx.x & 7;
    int slot = blockIdx.x >> 3;
    int vblk = xcd * (NSPAT / 8) + slot;
    int bx   = vblk & (NBX - 1);
    int by   = (vblk >> 3) & (NBY - 1);
    int b    = vblk >> 7;
    int x0 = bx * BX, y0 = by * BY;
    int lane = t & 63, wv = t >> 6;
    int x  = x0 + lane;                  // this thread's x (all 4 px share it)
    int yb = y0 + wv * 4;                // px p of this thread = row yb + p

    // Tile origin, clamped fully inside the image (staging needs no clamps).
    // colbase stays float4-aligned (x0 mult of 64, W-TW = 424 mult of 4).
    int rowbase = min(max(y0 - 10, 0), H - TH);
    int colbase = min(max(x0 - 12, 0), W - TW);

    const float* pl0 = pred + (size_t)(b * R + 0) * C * HW;
    const float* pl1 = pred + (size_t)(b * R + 1) * C * HW;
    const float* st0 = pl0 + (size_t)rowbase * W + colbase;
    const float* st1 = pl1 + (size_t)rowbase * W + colbase;

    int cbeg = (C * blockIdx.y) / NCHUNK;        // {0,4,9,14}
    int cend = (C * (blockIdx.y + 1)) / NCHUNK;  // {4,9,14,19}
    int nch  = cend - cbeg;                      // 4 or 5, block-uniform

    // Stage one channel (both refs) into the tile pair. Wave-linear DMA.
    auto STAGE = [&](int c) {
        const float* s0 = st0 + (size_t)c * HW;
        const float* s1 = st1 + (size_t)c * HW;
        #pragma unroll
        for (int i2 = 0; i2 < 4; ++i2) {
            int idx = t + i2 * 256;
            if (idx < TILE_V4) {
                int row = idx / 22;               // 22 float4s per tile row
                int off = idx * 4 + row * (W - TW);   // == row*W + c4
                GLD_LDS16(s0 + off, &tiles[0][idx * 4]);
                GLD_LDS16(s1 + off, &tiles[1][idx * 4]);
            }
        }
    };

    // Prologue: stage the first channel now; it overlaps the ~300-op tap
    // setup below and is drained by the first loop-body __syncthreads().
    STAGE(cbeg);

    // Per-(ref, px) tap state: two row-pair offsets + 4 pair weights.
    int   off0[R][4], off1[R][4];
    int   offL0[R][4], offL1[R][4], offG0[R][4], offG1[R][4];
    float wq[R][4][4];
    int flag = 0;

    #pragma unroll
    for (int r = 0; r < R; ++r) {
        const float* mvx = mv + (size_t)((b * R + r) * 2) * HW;
        const float* mvy = mvx + HW;
        const float* wp  = wgt + (size_t)(b * R + r) * HW;
        #pragma unroll
        for (int p = 0; p < 4; ++p) {
            int yy = yb + p;
            size_t ro = (size_t)yy * W + x;       // 256B-coalesced per wave
            float mx = mvx[ro], my = mvy[ro], wr = wp[ro];

            float gx = (float)x  + mx * 0.25f;    // quarter-pel -> pixel
            float gy = (float)yy + my * 0.25f;
            float fx0 = floorf(gx), fy0 = floorf(gy);
            float wx1 = gx - fx0, wx0 = 1.0f - wx1;
            float wy1 = gy - fy0, wy0 = 1.0f - wy1;
            int ix0 = (int)fx0, iy0 = (int)fy0;
            int ix1 = ix0 + 1,  iy1 = iy0 + 1;

            // x pair: shift base into [0, W-2], route wx0/wx1 per element.
            int base = min(max(ix0, 0), W - 2);
            float wA = (ix0 == base)     ? wx0 : ((ix1 == base)     ? wx1 : 0.0f);
            float wB = (ix1 == base + 1) ? wx1 : ((ix0 == base + 1) ? wx0 : 0.0f);
            float wy0v = ((iy0 >= 0) && (iy0 < H)) ? wy0 * wr : 0.0f;
            float wy1v = ((iy1 >= 0) && (iy1 < H)) ? wy1 * wr : 0.0f;
            int cy0 = min(max(iy0, 0), H - 1);
            int cy1 = min(max(iy1, 0), H - 1);

            int l0 = base - colbase;
            int r0 = cy0 - rowbase, r1 = cy1 - rowbase;
            bool anyx = (wA != 0.0f) || (wB != 0.0f);
            bool anyy = (wy0v != 0.0f) || (wy1v != 0.0f);
            bool cb  = (l0 < 0 || l0 > TW - 2) && anyx && anyy;
            bool rb0 = (r0 < 0 || r0 > TH - 1) && (wy0v != 0.0f) && anyx;
            bool rb1 = (r1 < 0 || r1 > TH - 1) && (wy1v != 0.0f) && anyx;
            flag |= (int)(cb || rb0 || rb1);
            l0 = min(max(l0, 0), TW - 2);
            r0 = min(max(r0, 0), TH - 1);
            r1 = min(max(r1, 0), TH - 1);

            offL0[r][p] = r0 * TW + l0;
            offL1[r][p] = r1 * TW + l0;
            offG0[r][p] = cy0 * W + base;
            offG1[r][p] = cy1 * W + base;
            wq[r][p][0] = wy0v * wA;
            wq[r][p][1] = wy0v * wB;
            wq[r][p][2] = wy1v * wA;
            wq[r][p][3] = wy1v * wB;
        }
    }

    // Block-uniform fallback: if ANY tap escaped the halo, the whole block
    // uses global gathers instead of LDS. Flag reduction ONLY — memory
    // ordering comes from the plain __syncthreads() in the loop.
    int fbB = __syncthreads_or(flag);
    #pragma unroll
    for (int r = 0; r < R; ++r)
        #pragma unroll
        for (int p = 0; p < 4; ++p) {
            off0[r][p] = fbB ? offG0[r][p] : offL0[r][p];
            off1[r][p] = fbB ? offG1[r][p] : offL1[r][p];
        }

    // Per-channel results accumulate here; stored only in the epilogue so no
    // loop-top vmcnt(0) ever waits on an output store. STATIC indexing only
    // (i is an unroll constant) — runtime indexing would go to scratch.
    float res[MAXCH][4];

    #pragma unroll
    for (int i = 0; i < MAXCH; ++i) {
        if (i < nch) {                   // block-uniform guard (barriers safe)
            int c = cbeg + i;
            if (i > 0) {
                __syncthreads();         // compute(i-1)'s LDS readers done
                if (!fbB) STAGE(c);      // re-stage over the single buffer
            }
            __syncthreads();             // drains stage (vmcnt0 + barrier)

            __builtin_amdgcn_s_setprio(1);   // favor gather+FMA waves over
                                             // other blocks' staging issue
            if (!fbB) {
                const float* tb0 = &tiles[0][0];
                const float* tb1 = &tiles[1][0];
                #pragma unroll
                for (int p = 0; p < 4; ++p) {
                    float a00 = tb0[off0[0][p]], a01 = tb0[off0[0][p] + 1];
                    float a10 = tb0[off1[0][p]], a11 = tb0[off1[0][p] + 1];
                    float b00 = tb1[off0[1][p]], b01 = tb1[off0[1][p] + 1];
                    float b10 = tb1[off1[1][p]], b11 = tb1[off1[1][p] + 1];
                    res[i][p] = wq[0][p][0] * a00 + wq[0][p][1] * a01
                              + wq[0][p][2] * a10 + wq[0][p][3] * a11
                              + wq[1][p][0] * b00 + wq[1][p][1] * b01
                              + wq[1][p][2] * b10 + wq[1][p][3] * b11;
                }
            } else {
                const float* pc0 = pl0 + (size_t)c * HW;
                const float* pc1 = pl1 + (size_t)c * HW;
                #pragma unroll
                for (int p = 0; p < 4; ++p) {
                    float a00 = pc0[off0[0][p]], a01 = pc0[off0[0][p] + 1];
                    float a10 = pc0[off1[0][p]], a11 = pc0[off1[0][p] + 1];
                    float b00 = pc1[off0[1][p]], b01 = pc1[off0[1][p] + 1];
                    float b10 = pc1[off1[1][p]], b11 = pc1[off1[1][p] + 1];
                    res[i][p] = wq[0][p][0] * a00 + wq[0][p][1] * a01
                              + wq[0][p][2] * a10 + wq[0][p][3] * a11
                              + wq[1][p][0] * b00 + wq[1][p][1] * b01
                              + wq[1][p][2] * b10 + wq[1][p][3] * b11;
                }
            }
            __builtin_amdgcn_s_setprio(0);
        }
    }

    // Barrier-free epilogue: all output stores issue back-to-back; the only
    // drain is the implicit one at kernel end. 256B-coalesced wave stores.
    float* ob = out + (size_t)b * C * HW + (size_t)yb * W + x;
    #pragma unroll
    for (int i = 0; i < MAXCH; ++i) {
        if (i < nch) {
            float* oc = ob + (size_t)(cbeg + i) * HW;
            #pragma unroll
            for (int p = 0; p < 4; ++p)
                oc[(size_t)p * W] = res[i][p];
        }
    }
}

extern "C" void kernel_launch(void* const* d_in, const int* in_sizes, int n_in,
                              void* d_out, int out_size, void* d_ws, size_t ws_size,
                              hipStream_t stream) {
    const float* pred = (const float*)d_in[0];   // [B,R,C,H,W] fp32
    const float* mv   = (const float*)d_in[1];   // [B,R,2,H,W] fp32
    const float* wgt  = (const float*)d_in[2];   // [B,R,1,H,W] fp32
    float* out = (float*)d_out;                  // [B,C,H,W] fp32

    dim3 grid(NSPAT, NCHUNK);            // 512 spatial tiles x 4 channel chunks
    mc_warp_kernel<<<grid, dim3(256), 0, stream>>>(pred, mv, wgt, out);
}